// Round 1
// baseline (829.405 us; speedup 1.0000x reference)
//
#include <hip/hip_runtime.h>
#include <hip/hip_bf16.h>

#define DEVINL __device__ __forceinline__

constexpr int N = 50000;
constexpr int E = 800000;
constexpr int F_IN = 128;
constexpr int H = 96;
constexpr int C = 16;
constexpr int G = 128;
constexpr int S = 8;      // pooling chunks per graph
constexpr int ELLW = 64;  // ELL width: deg ~ Poisson(16), P(>64) ~ 1e-20

// fp32 weight table layout in ws
constexpr int OFF_W0  = 0;                    // [128][96]
constexpr int OFF_W1  = OFF_W0 + F_IN * H;    // [96][96]
constexpr int OFF_W2  = OFF_W1 + H * H;
constexpr int OFF_WC1 = OFF_W2 + H * H;       // [192][96]
constexpr int OFF_WC2 = OFF_WC1 + 2 * H * H;  // [96][16]
constexpr int OFF_B0  = OFF_WC2 + H * C;
constexpr int OFF_B1  = OFF_B0 + H;
constexpr int OFF_B2  = OFF_B1 + H;
constexpr int OFF_BC1 = OFF_B2 + H;
constexpr int OFF_BC2 = OFF_BC1 + H;
constexpr int WF_TOT  = OFF_BC2 + C;          // 51088 floats

constexpr int CVB   = (WF_TOT + 255) / 256;   // weight-convert blocks (200)
constexpr int EB    = (E / 4 + 255) / 256;    // edge i32-compaction blocks (782)
constexpr int GEMB  = (N + 31) / 32;          // gemm blocks (1563)
constexpr int SCANB = 256;                    // node-range scan blocks
constexpr int PB    = (N + SCANB - 1) / SCANB; // 196 nodes owned per scan block

DEVINL float gelu_f(float x) {
    return 0.5f * x * (1.0f + erff(x * 0.70710678118654752440f));
}

// ---------------- inline dtype detection (broadcast loads, ~free) ----------------
DEVINL int detect_eidx_i64(const int* e) {
    int z = 0;
#pragma unroll
    for (int i = 1; i < 16; i += 2) z |= e[i];
    return z == 0;
}
DEVINL int detect_batch_i64(const int* a) {
    int z = 0;
    for (int i = 20001; i < 20032; i += 2) z |= a[i];
    return z == 0;
}
DEVINL int detect_x_f32(const unsigned short* xu) {
    int bad = 0;
    for (int i = 0; i < 128; i += 2) { int ex = (xu[i] >> 7) & 0xFF; if (ex >= 132) bad = 1; }
    return bad;
}

// ---------------- bf16 pack/unpack ----------------
DEVINL unsigned pk(float a, float b) {
    __hip_bfloat16 ha = __float2bfloat16(a), hb = __float2bfloat16(b);
    unsigned short ua = *(unsigned short*)&ha, ub = *(unsigned short*)&hb;
    return (unsigned)ua | ((unsigned)ub << 16);
}
DEVINL float lo16(unsigned u) { return __uint_as_float(u << 16); }
DEVINL float hi16(unsigned u) { return __uint_as_float(u & 0xffff0000u); }

DEVINL float disv(int c) { return rsqrtf((float)c + 2.0f); }

// ---------------- weight convert + edge i64->i32 compaction ----------------
// Blocks [0,CVB): convert weights to fp32 table.
// Blocks [CVB,CVB+EB): compact src/dst indices to i32 (halves scan volume in k_sg).
// cnt zeroing dropped: k_sg scan blocks write cnt[n] exactly once for every n.
__global__ void k_prep(const void* W0, const void* W1, const void* W2,
                       const void* Wc1, const void* Wc2,
                       const void* b0, const void* b1, const void* b2,
                       const void* bc1, const void* bc2,
                       const void* x, const int* __restrict__ eidx,
                       float* __restrict__ wf,
                       int* __restrict__ src32, int* __restrict__ dst32) {
    int b = blockIdx.x, t = threadIdx.x;
    if (b >= CVB) {
        int i = (b - CVB) * 256 + t;        // quad-of-edges index
        if (4 * i >= E) return;
        int i64 = detect_eidx_i64(eidx);
        int4 s4, d4;
        if (i64) {
            int4 a0 = *(const int4*)(eidx + 8 * i);
            int4 a1 = *(const int4*)(eidx + 8 * i + 4);
            s4 = make_int4(a0.x, a0.z, a1.x, a1.z);
            int4 c0 = *(const int4*)(eidx + 2 * E + 8 * i);
            int4 c1 = *(const int4*)(eidx + 2 * E + 8 * i + 4);
            d4 = make_int4(c0.x, c0.z, c1.x, c1.z);
        } else {
            s4 = *(const int4*)(eidx + 4 * i);
            d4 = *(const int4*)(eidx + E + 4 * i);
        }
        *(int4*)(src32 + 4 * i) = s4;
        *(int4*)(dst32 + 4 * i) = d4;
        return;
    }
    int i = b * 256 + t;
    if (i >= WF_TOT) return;
    int f32 = detect_x_f32((const unsigned short*)x);
    const void* src; int j;
    if      (i < OFF_W1)  { src = W0;  j = i - OFF_W0; }
    else if (i < OFF_W2)  { src = W1;  j = i - OFF_W1; }
    else if (i < OFF_WC1) { src = W2;  j = i - OFF_W2; }
    else if (i < OFF_WC2) { src = Wc1; j = i - OFF_WC1; }
    else if (i < OFF_B0)  { src = Wc2; j = i - OFF_WC2; }
    else if (i < OFF_B1)  { src = b0;  j = i - OFF_B0; }
    else if (i < OFF_B2)  { src = b1;  j = i - OFF_B1; }
    else if (i < OFF_BC1) { src = b2;  j = i - OFF_B2; }
    else if (i < OFF_BC2) { src = bc1; j = i - OFF_BC1; }
    else                  { src = bc2; j = i - OFF_BC2; }
    wf[i] = f32 ? ((const float*)src)[j]
                : __bfloat162float(((const __hip_bfloat16*)src)[j]);
}

// ---------------- GEMM tile: out_bf16 [N][48 uints]; optional dis-prescale from cnt ----------------
template<int K, int KC, bool RAW_IN, bool GELU_IN, bool SCALE_OUT>
DEVINL void gemm_tile(const void* __restrict__ inp, const float* __restrict__ Wf,
                      const int* __restrict__ cnt,
                      int xf32, unsigned* __restrict__ out, int bid, int t) {
    constexpr int R = 32;
    constexpr int NC = K / KC;
    __shared__ __align__(16) float xs[KC][R + 4];
    __shared__ __align__(16) float wsh[KC * 96];
    const int r0 = bid * R;
    const int ty = t >> 4;
    const int tx = t & 15;

    float acc[4][6];
#pragma unroll
    for (int i = 0; i < 4; ++i)
#pragma unroll
        for (int j = 0; j < 6; ++j) acc[i][j] = 0.f;

    for (int c = 0; c < NC; ++c) {
        if (c) __syncthreads();
        for (int idx = t * 4; idx < KC * 96; idx += 128 * 4)
            *(float4*)&wsh[idx] = *(const float4*)&Wf[c * KC * 96 + idx];
        if (RAW_IN && !xf32) {
            for (int idx = t; idx < R * KC; idx += 128) {
                int r = idx / KC, kk = idx - r * KC;
                int row = r0 + r, k = c * KC + kk;
                float v = 0.f;
                if (row < N) v = __bfloat162float(((const __hip_bfloat16*)inp)[(size_t)row * K + k]);
                xs[kk][r] = v;
            }
        } else {
            constexpr int KC4 = KC / 4;
            for (int idx = t; idx < R * KC4; idx += 128) {
                int r = idx / KC4, k4 = (idx - r * KC4) * 4;
                int row = r0 + r, k = c * KC + k4;
                float4 v = make_float4(0.f, 0.f, 0.f, 0.f);
                if (row < N) v = *(const float4*)((const float*)inp + (size_t)row * K + k);
                if (GELU_IN) { v.x = gelu_f(v.x); v.y = gelu_f(v.y); v.z = gelu_f(v.z); v.w = gelu_f(v.w); }
                xs[k4 + 0][r] = v.x; xs[k4 + 1][r] = v.y; xs[k4 + 2][r] = v.z; xs[k4 + 3][r] = v.w;
            }
        }
        __syncthreads();

#pragma unroll 4
        for (int kk = 0; kk < KC; ++kk) {
            float4 av = *(const float4*)&xs[kk][ty * 4];
            float2 b0 = *(const float2*)&wsh[kk * 96 + tx * 6];
            float2 b1 = *(const float2*)&wsh[kk * 96 + tx * 6 + 2];
            float2 b2 = *(const float2*)&wsh[kk * 96 + tx * 6 + 4];
            float a[4] = {av.x, av.y, av.z, av.w};
            float b[6] = {b0.x, b0.y, b1.x, b1.y, b2.x, b2.y};
#pragma unroll
            for (int i = 0; i < 4; ++i)
#pragma unroll
                for (int j = 0; j < 6; ++j)
                    acc[i][j] = fmaf(a[i], b[j], acc[i][j]);
        }
    }

#pragma unroll
    for (int i = 0; i < 4; ++i) {
        int row = r0 + ty * 4 + i;
        if (row < N) {
            float d = SCALE_OUT ? disv(cnt[row]) : 1.0f;
            unsigned* o = out + (size_t)row * 48 + tx * 3;
            o[0] = pk(d * acc[i][0], d * acc[i][1]);
            o[1] = pk(d * acc[i][2], d * acc[i][3]);
            o[2] = pk(d * acc[i][4], d * acc[i][5]);
        }
    }
}

// ---------------- fused: node-range scan ELL build (LDS atomics) + gemm layer 0 ----------------
// NOTE (r15): old edge-parallel build was bound by GLOBAL returned atomics — device-scope
// RMW resolves memory-side (XCD L2s non-coherent), each scattered 4B atomic dirtied a 64B
// line (WRITE_SIZE 57.6MB for ~13MB payload). New scheme: SCANB=256 blocks each OWN
// PB=196 nodes, stream the full i32 dst list (3.2MB, L2-resident per XCD), and claim ELL
// slots via LDS ds_add_rtn. cnt written once per node at the end — no global atomics at all.
// Scan blocks interleaved stride-7 with gemm blocks (gcd(7,256)=1 -> one scan block/CU).
__global__ __launch_bounds__(128) void k_sg(const void* __restrict__ x,
                                            const float* __restrict__ Wf,
                                            const int* __restrict__ src32,
                                            const int* __restrict__ dst32,
                                            int* __restrict__ cnt, int* __restrict__ ell,
                                            unsigned* __restrict__ outZ) {
    int b = blockIdx.x, t = threadIdx.x;
    int q = b / 7, r = b % 7;
    if (r == 0 && q < SCANB) {
        __shared__ int lcnt[PB];
        int lo = q * PB;
        int hi = min(lo + PB, N);
        int nloc = hi - lo;
        for (int i = t; i < PB; i += 128) lcnt[i] = 0;
        __syncthreads();
        for (int base = t * 8; base < E; base += 128 * 8) {
            int4 a0 = *(const int4*)(dst32 + base);
            int4 a1 = *(const int4*)(dst32 + base + 4);
            int ds[8] = {a0.x, a0.y, a0.z, a0.w, a1.x, a1.y, a1.z, a1.w};
#pragma unroll
            for (int k = 0; k < 8; ++k) {
                unsigned rel = (unsigned)(ds[k] - lo);
                if (rel < (unsigned)nloc) {
                    int p = atomicAdd(&lcnt[rel], 1);
                    int s = src32[base + k];
                    if (p < ELLW) ell[ds[k] * ELLW + p] = s;
                }
            }
        }
        __syncthreads();
        for (int i = t; i < nloc; i += 128) cnt[lo + i] = lcnt[i];
        return;
    }
    int nsb = min(q + (r ? 1 : 0), SCANB);
    int gb = b - nsb;
    if (gb >= GEMB) return;
    int xf32 = detect_x_f32((const unsigned short*)x);
    gemm_tile<F_IN, 32, true, false, false>(x, Wf, nullptr, xf32, outZ, gb, t);
}

// ---------------- standalone gemm (layers 1,2: fp32 in + gelu, dis-prescaled bf16 out) ----------------
template<int K, int KC, bool GELU_IN>
__global__ __launch_bounds__(128) void k_gemm(const float* __restrict__ inp,
                                              const float* __restrict__ Wf,
                                              const int* __restrict__ cnt,
                                              unsigned* __restrict__ out) {
    gemm_tile<K, KC, false, GELU_IN, true>(inp, Wf, cnt, 1, out, blockIdx.x, threadIdx.x);
}

// ---------------- aggregation: 5 edge-slots x 12 lanes, uint4, 3-deep unroll ----------------
// PRESCALED (layers 1,2): xw rows carry dis[src] -> pure adds. Layer 0 computes
// per-edge rsqrt(cnt[s]+2) inline (cnt gather == old dis gather cost; kills k_dis).
// h = res + dn*sum + (PRESCALED ? 2*dn : 2*dn*dn)*self + b.
template<bool PRESCALED>
__global__ __launch_bounds__(256) void k_aggr(const unsigned* __restrict__ xw, const float* res,
                                              const int* __restrict__ ell, const int* __restrict__ cnt,
                                              const float* __restrict__ bias, float* __restrict__ out) {
    int wid = threadIdx.x >> 6, lane = threadIdx.x & 63;
    int n = blockIdx.x * 4 + wid;
    if (n >= N) return;
    int cn = cnt[n];
    int e0 = n * ELLW;
    int e1 = e0 + min(cn, ELLW);
    int slot = lane / 12;            // 0..4 active; lanes 60-63 idle
    int li = lane - slot * 12;       // 0..11
    int cp = li * 4;                 // uint index (uint4/lane; 12*16B = 192B row)
    float4 A0 = make_float4(0.f, 0.f, 0.f, 0.f);
    float4 A1 = make_float4(0.f, 0.f, 0.f, 0.f);
    int eb = (slot < 5) ? (e0 + slot) : e1;
    for (; eb + 10 < e1; eb += 15) {   // 3-deep: executes for deg ~16 (3+ edges/slot)
        int s0 = ell[eb];
        int s1 = ell[eb + 5];
        int s2 = ell[eb + 10];
        uint4 u0 = *(const uint4*)(xw + (size_t)s0 * 48 + cp);
        uint4 u1 = *(const uint4*)(xw + (size_t)s1 * 48 + cp);
        uint4 u2 = *(const uint4*)(xw + (size_t)s2 * 48 + cp);
        if (PRESCALED) {
            A0.x += lo16(u0.x) + lo16(u1.x) + lo16(u2.x);
            A0.y += hi16(u0.x) + hi16(u1.x) + hi16(u2.x);
            A0.z += lo16(u0.y) + lo16(u1.y) + lo16(u2.y);
            A0.w += hi16(u0.y) + hi16(u1.y) + hi16(u2.y);
            A1.x += lo16(u0.z) + lo16(u1.z) + lo16(u2.z);
            A1.y += hi16(u0.z) + hi16(u1.z) + hi16(u2.z);
            A1.z += lo16(u0.w) + lo16(u1.w) + lo16(u2.w);
            A1.w += hi16(u0.w) + hi16(u1.w) + hi16(u2.w);
        } else {
            float w0 = disv(cnt[s0]), w1 = disv(cnt[s1]), w2 = disv(cnt[s2]);
            A0.x = fmaf(w0, lo16(u0.x), A0.x); A0.y = fmaf(w0, hi16(u0.x), A0.y);
            A0.z = fmaf(w0, lo16(u0.y), A0.z); A0.w = fmaf(w0, hi16(u0.y), A0.w);
            A1.x = fmaf(w0, lo16(u0.z), A1.x); A1.y = fmaf(w0, hi16(u0.z), A1.y);
            A1.z = fmaf(w0, lo16(u0.w), A1.z); A1.w = fmaf(w0, hi16(u0.w), A1.w);
            A0.x = fmaf(w1, lo16(u1.x), A0.x); A0.y = fmaf(w1, hi16(u1.x), A0.y);
            A0.z = fmaf(w1, lo16(u1.y), A0.z); A0.w = fmaf(w1, hi16(u1.y), A0.w);
            A1.x = fmaf(w1, lo16(u1.z), A1.x); A1.y = fmaf(w1, hi16(u1.z), A1.y);
            A1.z = fmaf(w1, lo16(u1.w), A1.z); A1.w = fmaf(w1, hi16(u1.w), A1.w);
            A0.x = fmaf(w2, lo16(u2.x), A0.x); A0.y = fmaf(w2, hi16(u2.x), A0.y);
            A0.z = fmaf(w2, lo16(u2.y), A0.z); A0.w = fmaf(w2, hi16(u2.y), A0.w);
            A1.x = fmaf(w2, lo16(u2.z), A1.x); A1.y = fmaf(w2, hi16(u2.z), A1.y);
            A1.z = fmaf(w2, lo16(u2.w), A1.z); A1.w = fmaf(w2, hi16(u2.w), A1.w);
        }
    }
    for (; eb < e1; eb += 5) {
        int s = ell[eb];
        uint4 u = *(const uint4*)(xw + (size_t)s * 48 + cp);
        if (PRESCALED) {
            A0.x += lo16(u.x); A0.y += hi16(u.x); A0.z += lo16(u.y); A0.w += hi16(u.y);
            A1.x += lo16(u.z); A1.y += hi16(u.z); A1.z += lo16(u.w); A1.w += hi16(u.w);
        } else {
            float w = disv(cnt[s]);
            A0.x = fmaf(w, lo16(u.x), A0.x); A0.y = fmaf(w, hi16(u.x), A0.y);
            A0.z = fmaf(w, lo16(u.y), A0.z); A0.w = fmaf(w, hi16(u.y), A0.w);
            A1.x = fmaf(w, lo16(u.z), A1.x); A1.y = fmaf(w, hi16(u.z), A1.y);
            A1.z = fmaf(w, lo16(u.w), A1.z); A1.w = fmaf(w, hi16(u.w), A1.w);
        }
    }
    // reduce across 5 slots (pre-gather originals; lanes 0-11 hold the result)
    {
        float g0, g1, g2, g3;
        g0 = __shfl(A0.x, lane + 12); g1 = __shfl(A0.x, lane + 24); g2 = __shfl(A0.x, lane + 36); g3 = __shfl(A0.x, lane + 48);
        A0.x += g0 + g1 + g2 + g3;
        g0 = __shfl(A0.y, lane + 12); g1 = __shfl(A0.y, lane + 24); g2 = __shfl(A0.y, lane + 36); g3 = __shfl(A0.y, lane + 48);
        A0.y += g0 + g1 + g2 + g3;
        g0 = __shfl(A0.z, lane + 12); g1 = __shfl(A0.z, lane + 24); g2 = __shfl(A0.z, lane + 36); g3 = __shfl(A0.z, lane + 48);
        A0.z += g0 + g1 + g2 + g3;
        g0 = __shfl(A0.w, lane + 12); g1 = __shfl(A0.w, lane + 24); g2 = __shfl(A0.w, lane + 36); g3 = __shfl(A0.w, lane + 48);
        A0.w += g0 + g1 + g2 + g3;
        g0 = __shfl(A1.x, lane + 12); g1 = __shfl(A1.x, lane + 24); g2 = __shfl(A1.x, lane + 36); g3 = __shfl(A1.x, lane + 48);
        A1.x += g0 + g1 + g2 + g3;
        g0 = __shfl(A1.y, lane + 12); g1 = __shfl(A1.y, lane + 24); g2 = __shfl(A1.y, lane + 36); g3 = __shfl(A1.y, lane + 48);
        A1.y += g0 + g1 + g2 + g3;
        g0 = __shfl(A1.z, lane + 12); g1 = __shfl(A1.z, lane + 24); g2 = __shfl(A1.z, lane + 36); g3 = __shfl(A1.z, lane + 48);
        A1.z += g0 + g1 + g2 + g3;
        g0 = __shfl(A1.w, lane + 12); g1 = __shfl(A1.w, lane + 24); g2 = __shfl(A1.w, lane + 36); g3 = __shfl(A1.w, lane + 48);
        A1.w += g0 + g1 + g2 + g3;
    }

    if (lane < 12) {
        float dn = disv(cn);
        float sc = PRESCALED ? (2.f * dn) : (2.f * dn * dn);
        int cl = li * 8;
        uint4 su = *(const uint4*)(xw + (size_t)n * 48 + cp);
        float4 sv0 = make_float4(lo16(su.x), hi16(su.x), lo16(su.y), hi16(su.y));
        float4 sv1 = make_float4(lo16(su.z), hi16(su.z), lo16(su.w), hi16(su.w));
        float4 bv0 = *(const float4*)(bias + cl);
        float4 bv1 = *(const float4*)(bias + cl + 4);
        float4 rv0 = make_float4(0.f, 0.f, 0.f, 0.f);
        float4 rv1 = make_float4(0.f, 0.f, 0.f, 0.f);
        if (res) {
            rv0 = *(const float4*)(res + (size_t)n * 96 + cl);
            rv1 = *(const float4*)(res + (size_t)n * 96 + cl + 4);
        }
        float4 o0, o1;
        o0.x = rv0.x + dn * A0.x + sc * sv0.x + bv0.x;
        o0.y = rv0.y + dn * A0.y + sc * sv0.y + bv0.y;
        o0.z = rv0.z + dn * A0.z + sc * sv0.z + bv0.z;
        o0.w = rv0.w + dn * A0.w + sc * sv0.w + bv0.w;
        o1.x = rv1.x + dn * A1.x + sc * sv1.x + bv1.x;
        o1.y = rv1.y + dn * A1.y + sc * sv1.y + bv1.y;
        o1.z = rv1.z + dn * A1.z + sc * sv1.z + bv1.z;
        o1.w = rv1.w + dn * A1.w + sc * sv1.w + bv1.w;
        *(float4*)(out + (size_t)n * 96 + cl) = o0;
        *(float4*)(out + (size_t)n * 96 + cl + 4) = o1;
    }
}

// ---------------- pooling ----------------
DEVINL int ld_idx(const int* a, int i64, int i) { return i64 ? a[2 * i] : a[i]; }

DEVINL int lbound_s(const int* a, int i64, int n, int key) {
    int lo = 0, hi = n;
    while (lo < hi) { int m = (lo + hi) >> 1; if (ld_idx(a, i64, m) < key) lo = m + 1; else hi = m; }
    return lo;
}

__global__ __launch_bounds__(128) void k_pool(const float* __restrict__ h, const int* __restrict__ batch,
                                              float* __restrict__ part) {
    int i64 = detect_batch_i64(batch);
    int g = blockIdx.x / S, sch = blockIdx.x % S;
    int lo = lbound_s(batch, i64, N, g), hi = lbound_s(batch, i64, N, g + 1);
    int len = hi - lo;
    int a = lo + (int)(((long long)len * sch) / S);
    int b = lo + (int)(((long long)len * (sch + 1)) / S);
    int t = threadIdx.x;
    if (t < 96) {
        float s0 = 0.f, s1 = 0.f, m0 = -INFINITY, m1 = -INFINITY;
        int n = a;
        for (; n + 1 < b; n += 2) {
            float v0 = gelu_f(h[(size_t)n * 96 + t]);
            float v1 = gelu_f(h[(size_t)(n + 1) * 96 + t]);
            s0 += v0; s1 += v1;
            m0 = fmaxf(m0, v0); m1 = fmaxf(m1, v1);
        }
        if (n < b) {
            float v = gelu_f(h[(size_t)n * 96 + t]);
            s0 += v; m0 = fmaxf(m0, v);
        }
        part[(size_t)blockIdx.x * 192 + t] = s0 + s1;
        part[(size_t)blockIdx.x * 192 + 96 + t] = fmaxf(m0, m1);
    }
}

// ---------------- classifier head ----------------
__global__ __launch_bounds__(128) void k_cls(const float* __restrict__ part, const int* __restrict__ batch,
                                             const void* __restrict__ x,
                                             const float* __restrict__ wf, void* __restrict__ outp) {
    __shared__ float p[192];
    __shared__ float q[96];
    int i64 = detect_batch_i64(batch);
    int g = blockIdx.x, t = threadIdx.x;
    int lo = lbound_s(batch, i64, N, g), hi = lbound_s(batch, i64, N, g + 1);
    float inv = (hi > lo) ? 1.f / (float)(hi - lo) : 0.f;
    if (t < 96) {
        float sum = 0.f, mx = -INFINITY;
        for (int s = 0; s < S; ++s) {
            sum += part[(size_t)(g * S + s) * 192 + t];
            mx = fmaxf(mx, part[(size_t)(g * S + s) * 192 + 96 + t]);
        }
        p[t] = sum * inv;
        p[96 + t] = mx;
    }
    __syncthreads();
    if (t < 96) {
        float acc = wf[OFF_BC1 + t];
        const float* Wc1 = wf + OFF_WC1;
        for (int j = 0; j < 192; ++j)
            acc += p[j] * Wc1[j * 96 + t];
        q[t] = gelu_f(acc);
    }
    __syncthreads();
    if (t < 16) {
        float acc = wf[OFF_BC2 + t];
        const float* Wc2 = wf + OFF_WC2;
        for (int j = 0; j < 96; ++j)
            acc += q[j] * Wc2[j * 16 + t];
        if (detect_x_f32((const unsigned short*)x)) ((float*)outp)[g * 16 + t] = acc;
        else ((__hip_bfloat16*)outp)[g * 16 + t] = __float2bfloat16(acc);
    }
}

extern "C" void kernel_launch(void* const* d_in, const int* in_sizes, int n_in,
                              void* d_out, int out_size, void* d_ws, size_t ws_size,
                              hipStream_t stream) {
    const void* x    = d_in[0];
    const int* eidx  = (const int*)d_in[1];
    const int* batch = (const int*)d_in[2];
    (void)in_sizes; (void)n_in; (void)out_size; (void)ws_size;

    char* w = (char*)d_ws;
    size_t off = 0;
    auto take = [&](size_t bytes) { size_t o = off; off += (bytes + 511) & ~(size_t)511; return o; };
    int*      cnt   = (int*)     (w + take((size_t)N * 4));
    float*    wf    = (float*)   (w + take((size_t)WF_TOT * 4));
    int*      ell   = (int*)     (w + take((size_t)N * ELLW * 4));   // 12.8 MB
    unsigned* bufA  = (unsigned*)(w + take((size_t)N * 48 * 4));     // bf16-pair packed xw
    float*    bufH  = (float*)   (w + take((size_t)N * 96 * 4));
    float*    part  = (float*)   (w + take((size_t)G * S * 192 * 4));
    int*      src32 = (int*)     (w + take((size_t)E * 4));          // 3.2 MB
    int*      dst32 = (int*)     (w + take((size_t)E * 4));          // 3.2 MB

    // 1: weight convert + edge i32 compaction
    k_prep<<<CVB + EB, 256, 0, stream>>>(d_in[3], d_in[5], d_in[7], d_in[9], d_in[11],
                                         d_in[4], d_in[6], d_in[8], d_in[10], d_in[12],
                                         x, eidx, wf, src32, dst32);
    // 2: fused node-range-scan ELL build (no global atomics) + gemm0
    k_sg<<<GEMB + SCANB, 128, 0, stream>>>(x, wf + OFF_W0, src32, dst32, cnt, ell, bufA);

    int aggr_grid = (N + 3) / 4;
    // 3-7: aggr/gemm chain
    k_aggr<false><<<aggr_grid, 256, 0, stream>>>(bufA, nullptr, ell, cnt, wf + OFF_B0, bufH);
    k_gemm<H, 48, true><<<GEMB, 128, 0, stream>>>(bufH, wf + OFF_W1, cnt, bufA);
    k_aggr<true><<<aggr_grid, 256, 0, stream>>>(bufA, bufH, ell, cnt, wf + OFF_B1, bufH);
    k_gemm<H, 48, true><<<GEMB, 128, 0, stream>>>(bufH, wf + OFF_W2, cnt, bufA);
    k_aggr<true><<<aggr_grid, 256, 0, stream>>>(bufA, bufH, ell, cnt, wf + OFF_B2, bufH);

    // 8-9: pooling + classifier
    k_pool<<<G * S, 128, 0, stream>>>(bufH, batch, part);
    k_cls<<<G, 128, 0, stream>>>(part, batch, x, wf, d_out);
}

// Round 3
// 354.714 us; speedup vs baseline: 2.3382x; 2.3382x over previous
//
#include <hip/hip_runtime.h>
#include <hip/hip_bf16.h>

#define DEVINL __device__ __forceinline__

constexpr int N = 50000;
constexpr int E = 800000;
constexpr int F_IN = 128;
constexpr int H = 96;
constexpr int C = 16;
constexpr int G = 128;
constexpr int S = 8;      // pooling chunks per graph
constexpr int ELLW = 64;  // ELL width: deg ~ Poisson(16), P(>64) ~ 1e-20

// fp32 weight table layout in ws
constexpr int OFF_W0  = 0;                    // [128][96]
constexpr int OFF_W1  = OFF_W0 + F_IN * H;    // [96][96]
constexpr int OFF_W2  = OFF_W1 + H * H;
constexpr int OFF_WC1 = OFF_W2 + H * H;       // [192][96]
constexpr int OFF_WC2 = OFF_WC1 + 2 * H * H;  // [96][16]
constexpr int OFF_B0  = OFF_WC2 + H * C;
constexpr int OFF_B1  = OFF_B0 + H;
constexpr int OFF_B2  = OFF_B1 + H;
constexpr int OFF_BC1 = OFF_B2 + H;
constexpr int OFF_BC2 = OFF_BC1 + H;
constexpr int WF_TOT  = OFF_BC2 + C;          // 51088 floats

constexpr int CVB   = (WF_TOT + 255) / 256;   // convert blocks (200, covers N for cnt-zero)
constexpr int GEMB  = (N + 31) / 32;          // gemm blocks (1563)
constexpr int SCATB = (E / 2 + 127) / 128;    // scatter blocks (3125)

DEVINL float gelu_f(float x) {
    return 0.5f * x * (1.0f + erff(x * 0.70710678118654752440f));
}

// ---------------- inline dtype detection (broadcast loads, ~free) ----------------
DEVINL int detect_eidx_i64(const int* e) {
    int z = 0;
#pragma unroll
    for (int i = 1; i < 16; i += 2) z |= e[i];
    return z == 0;
}
DEVINL int detect_batch_i64(const int* a) {
    int z = 0;
    for (int i = 20001; i < 20032; i += 2) z |= a[i];
    return z == 0;
}
DEVINL int detect_x_f32(const unsigned short* xu) {
    int bad = 0;
    for (int i = 0; i < 128; i += 2) { int ex = (xu[i] >> 7) & 0xFF; if (ex >= 132) bad = 1; }
    return bad;
}

// ---------------- bf16 pack/unpack ----------------
DEVINL unsigned pk(float a, float b) {
    __hip_bfloat16 ha = __float2bfloat16(a), hb = __float2bfloat16(b);
    unsigned short ua = *(unsigned short*)&ha, ub = *(unsigned short*)&hb;
    return (unsigned)ua | ((unsigned)ub << 16);
}
DEVINL float lo16(unsigned u) { return __uint_as_float(u << 16); }
DEVINL float hi16(unsigned u) { return __uint_as_float(u & 0xffff0000u); }

DEVINL float disv(int c) { return rsqrtf((float)c + 2.0f); }

// ---------------- weight convert + cnt zero (fused; covers N=50000 < 51200) ----------------
__global__ void k_prep(const void* W0, const void* W1, const void* W2,
                       const void* Wc1, const void* Wc2,
                       const void* b0, const void* b1, const void* b2,
                       const void* bc1, const void* bc2,
                       const void* x, float* __restrict__ wf, int* __restrict__ cnt) {
    int i = blockIdx.x * 256 + threadIdx.x;
    if (i < N) cnt[i] = 0;
    if (i >= WF_TOT) return;
    int f32 = detect_x_f32((const unsigned short*)x);
    const void* src; int j;
    if      (i < OFF_W1)  { src = W0;  j = i - OFF_W0; }
    else if (i < OFF_W2)  { src = W1;  j = i - OFF_W1; }
    else if (i < OFF_WC1) { src = W2;  j = i - OFF_W2; }
    else if (i < OFF_WC2) { src = Wc1; j = i - OFF_WC1; }
    else if (i < OFF_B0)  { src = Wc2; j = i - OFF_WC2; }
    else if (i < OFF_B1)  { src = b0;  j = i - OFF_B0; }
    else if (i < OFF_B2)  { src = b1;  j = i - OFF_B1; }
    else if (i < OFF_BC1) { src = b2;  j = i - OFF_B2; }
    else if (i < OFF_BC2) { src = bc1; j = i - OFF_BC1; }
    else                  { src = bc2; j = i - OFF_BC2; }
    wf[i] = f32 ? ((const float*)src)[j]
                : __bfloat162float(((const __hip_bfloat16*)src)[j]);
}

// ---------------- GEMM tile: out_bf16 [N][48 uints]; optional dis-prescale from cnt ----------------
template<int K, int KC, bool RAW_IN, bool GELU_IN, bool SCALE_OUT>
DEVINL void gemm_tile(const void* __restrict__ inp, const float* __restrict__ Wf,
                      const int* __restrict__ cnt,
                      int xf32, unsigned* __restrict__ out, int bid, int t) {
    constexpr int R = 32;
    constexpr int NC = K / KC;
    __shared__ __align__(16) float xs[KC][R + 4];
    __shared__ __align__(16) float wsh[KC * 96];
    const int r0 = bid * R;
    const int ty = t >> 4;
    const int tx = t & 15;

    float acc[4][6];
#pragma unroll
    for (int i = 0; i < 4; ++i)
#pragma unroll
        for (int j = 0; j < 6; ++j) acc[i][j] = 0.f;

    for (int c = 0; c < NC; ++c) {
        if (c) __syncthreads();
        for (int idx = t * 4; idx < KC * 96; idx += 128 * 4)
            *(float4*)&wsh[idx] = *(const float4*)&Wf[c * KC * 96 + idx];
        if (RAW_IN && !xf32) {
            for (int idx = t; idx < R * KC; idx += 128) {
                int r = idx / KC, kk = idx - r * KC;
                int row = r0 + r, k = c * KC + kk;
                float v = 0.f;
                if (row < N) v = __bfloat162float(((const __hip_bfloat16*)inp)[(size_t)row * K + k]);
                xs[kk][r] = v;
            }
        } else {
            constexpr int KC4 = KC / 4;
            for (int idx = t; idx < R * KC4; idx += 128) {
                int r = idx / KC4, k4 = (idx - r * KC4) * 4;
                int row = r0 + r, k = c * KC + k4;
                float4 v = make_float4(0.f, 0.f, 0.f, 0.f);
                if (row < N) v = *(const float4*)((const float*)inp + (size_t)row * K + k);
                if (GELU_IN) { v.x = gelu_f(v.x); v.y = gelu_f(v.y); v.z = gelu_f(v.z); v.w = gelu_f(v.w); }
                xs[k4 + 0][r] = v.x; xs[k4 + 1][r] = v.y; xs[k4 + 2][r] = v.z; xs[k4 + 3][r] = v.w;
            }
        }
        __syncthreads();

#pragma unroll 4
        for (int kk = 0; kk < KC; ++kk) {
            float4 av = *(const float4*)&xs[kk][ty * 4];
            float2 b0 = *(const float2*)&wsh[kk * 96 + tx * 6];
            float2 b1 = *(const float2*)&wsh[kk * 96 + tx * 6 + 2];
            float2 b2 = *(const float2*)&wsh[kk * 96 + tx * 6 + 4];
            float a[4] = {av.x, av.y, av.z, av.w};
            float b[6] = {b0.x, b0.y, b1.x, b1.y, b2.x, b2.y};
#pragma unroll
            for (int i = 0; i < 4; ++i)
#pragma unroll
                for (int j = 0; j < 6; ++j)
                    acc[i][j] = fmaf(a[i], b[j], acc[i][j]);
        }
    }

#pragma unroll
    for (int i = 0; i < 4; ++i) {
        int row = r0 + ty * 4 + i;
        if (row < N) {
            float d = SCALE_OUT ? disv(cnt[row]) : 1.0f;
            unsigned* o = out + (size_t)row * 48 + tx * 3;
            o[0] = pk(d * acc[i][0], d * acc[i][1]);
            o[1] = pk(d * acc[i][2], d * acc[i][3]);
            o[2] = pk(d * acc[i][4], d * acc[i][5]);
        }
    }
}

// ---------------- fused: direct ELL scatter + gemm layer 0 (r8 interleave) ----------------
// NOTE (r6-r14): scatter is returned-atomic-rate-bound (~58-72us fused), invariant
// to payload (r7), write locality (r10), counter count up (r14) — and WORSE with
// fewer counters (r11: 188us). Direct single-pass has lowest FETCH/VALU overhead.
// NOTE (r15 FAILED): replacing atomics with 256 node-range scan blocks (each streaming
// the full dst list) was 7x WORSE (~550us/block): latency-bound at 2 waves/block with
// 256x redundant L3 reads (819MB). Atomic scatter stays.
__global__ __launch_bounds__(128) void k_sg(const void* __restrict__ x,
                                            const float* __restrict__ Wf,
                                            const int* __restrict__ eidx,
                                            int* __restrict__ cnt, int* __restrict__ ell,
                                            unsigned* __restrict__ outZ) {
    int b = blockIdx.x, t = threadIdx.x;
    if (b % 3 == 0) {
        int gb = b / 3;
        if (gb >= GEMB) return;
        int xf32 = detect_x_f32((const unsigned short*)x);
        gemm_tile<F_IN, 32, true, false, false>(x, Wf, nullptr, xf32, outZ, gb, t);
        return;
    }
    int sb = (b / 3) * 2 + (b % 3) - 1;
    if (sb >= SCATB) return;
    int t2 = sb * 128 + t;
    int e = 2 * t2;
    if (e >= E) return;
    int i64 = detect_eidx_i64(eidx);
    int s0, s1, d0, d1;
    if (i64) {
        int4 sp = *(const int4*)(eidx + 4 * t2);
        int4 dp = *(const int4*)(eidx + 2 * E + 4 * t2);
        s0 = sp.x; s1 = sp.z; d0 = dp.x; d1 = dp.z;
    } else {
        int2 sp = *(const int2*)(eidx + 2 * t2);
        int2 dp = *(const int2*)(eidx + E + 2 * t2);
        s0 = sp.x; s1 = sp.y; d0 = dp.x; d1 = dp.y;
    }
    int p0 = atomicAdd(&cnt[d0], 1);
    if (p0 < ELLW) ell[d0 * ELLW + p0] = s0;
    if (e + 1 < E) {
        int p1 = atomicAdd(&cnt[d1], 1);
        if (p1 < ELLW) ell[d1 * ELLW + p1] = s1;
    }
}

// ---------------- standalone gemm (layers 1,2: fp32 in + gelu, dis-prescaled bf16 out) ----------------
template<int K, int KC, bool GELU_IN>
__global__ __launch_bounds__(128) void k_gemm(const float* __restrict__ inp,
                                              const float* __restrict__ Wf,
                                              const int* __restrict__ cnt,
                                              unsigned* __restrict__ out) {
    gemm_tile<K, KC, false, GELU_IN, true>(inp, Wf, cnt, 1, out, blockIdx.x, threadIdx.x);
}

// ---------------- aggregation: 5 edge-slots x 12 lanes, uint4, 3-deep unroll ----------------
// r17: LDS-staged ELL preload. One coalesced 64-lane load per wave fetches the node's
// whole ELL row into LDS (layer 0 additionally gathers cnt[idx] + rsqrt per lane into
// LDS). The hot loop reads indices/weights via ds_read broadcast (12 lanes/slot same
// addr -> broadcast; 5 slots -> 5 banks, conflict-free) — the 192B row gather is the
// only GLOBAL memory op per edge-step (was: global ell load -> [cnt gather ->] gather).
// NOTE (r16 FAILED): same idea via __shfl was WRONG — per-slot trip counts diverge and
// ds_bpermute returns undefined data from exec-masked-off source lanes. LDS reads have
// no active-lane requirement; loop structure and numerics identical to round-0.
// h = res + dn*sum + (PRESCALED ? 2*dn : 2*dn*dn)*self + b.
template<bool PRESCALED>
__global__ __launch_bounds__(256) void k_aggr(const unsigned* __restrict__ xw, const float* res,
                                              const int* __restrict__ ell, const int* __restrict__ cnt,
                                              const float* __restrict__ bias, float* __restrict__ out) {
    __shared__ int   sIdx[4][ELLW];
    __shared__ float sW[4][ELLW];
    int wid = threadIdx.x >> 6, lane = threadIdx.x & 63;
    int n = blockIdx.x * 4 + wid;
    if (n >= N) return;
    int cn = cnt[n];
    int cc = min(cn, ELLW);
    if (lane < cc) {
        int idx = ell[n * ELLW + lane];
        sIdx[wid][lane] = idx;
        if (!PRESCALED) sW[wid][lane] = disv(cnt[idx]);
    }
    // strictly wave-local LDS (each wave touches only its [wid] slice): no barrier
    // needed; compiler orders ds_write -> ds_read via lgkmcnt on the aliasing arrays.
    int slot = lane / 12;            // 0..4 active; lanes 60-63 idle
    int li = lane - slot * 12;       // 0..11
    int cp = li * 4;                 // uint index (uint4/lane; 12*16B = 192B row)
    float4 A0 = make_float4(0.f, 0.f, 0.f, 0.f);
    float4 A1 = make_float4(0.f, 0.f, 0.f, 0.f);
    int j = (slot < 5) ? slot : cc;  // edge ordinal for this slot
    for (; j + 10 < cc; j += 15) {   // 3-deep: executes for deg ~16 (3+ edges/slot)
        int s0 = sIdx[wid][j];
        int s1 = sIdx[wid][j + 5];
        int s2 = sIdx[wid][j + 10];
        uint4 u0 = *(const uint4*)(xw + (size_t)s0 * 48 + cp);
        uint4 u1 = *(const uint4*)(xw + (size_t)s1 * 48 + cp);
        uint4 u2 = *(const uint4*)(xw + (size_t)s2 * 48 + cp);
        if (PRESCALED) {
            A0.x += lo16(u0.x) + lo16(u1.x) + lo16(u2.x);
            A0.y += hi16(u0.x) + hi16(u1.x) + hi16(u2.x);
            A0.z += lo16(u0.y) + lo16(u1.y) + lo16(u2.y);
            A0.w += hi16(u0.y) + hi16(u1.y) + hi16(u2.y);
            A1.x += lo16(u0.z) + lo16(u1.z) + lo16(u2.z);
            A1.y += hi16(u0.z) + hi16(u1.z) + hi16(u2.z);
            A1.z += lo16(u0.w) + lo16(u1.w) + lo16(u2.w);
            A1.w += hi16(u0.w) + hi16(u1.w) + hi16(u2.w);
        } else {
            float w0 = sW[wid][j];
            float w1 = sW[wid][j + 5];
            float w2 = sW[wid][j + 10];
            A0.x = fmaf(w0, lo16(u0.x), A0.x); A0.y = fmaf(w0, hi16(u0.x), A0.y);
            A0.z = fmaf(w0, lo16(u0.y), A0.z); A0.w = fmaf(w0, hi16(u0.y), A0.w);
            A1.x = fmaf(w0, lo16(u0.z), A1.x); A1.y = fmaf(w0, hi16(u0.z), A1.y);
            A1.z = fmaf(w0, lo16(u0.w), A1.z); A1.w = fmaf(w0, hi16(u0.w), A1.w);
            A0.x = fmaf(w1, lo16(u1.x), A0.x); A0.y = fmaf(w1, hi16(u1.x), A0.y);
            A0.z = fmaf(w1, lo16(u1.y), A0.z); A0.w = fmaf(w1, hi16(u1.y), A0.w);
            A1.x = fmaf(w1, lo16(u1.z), A1.x); A1.y = fmaf(w1, hi16(u1.z), A1.y);
            A1.z = fmaf(w1, lo16(u1.w), A1.z); A1.w = fmaf(w1, hi16(u1.w), A1.w);
            A0.x = fmaf(w2, lo16(u2.x), A0.x); A0.y = fmaf(w2, hi16(u2.x), A0.y);
            A0.z = fmaf(w2, lo16(u2.y), A0.z); A0.w = fmaf(w2, hi16(u2.y), A0.w);
            A1.x = fmaf(w2, lo16(u2.z), A1.x); A1.y = fmaf(w2, hi16(u2.z), A1.y);
            A1.z = fmaf(w2, lo16(u2.w), A1.z); A1.w = fmaf(w2, hi16(u2.w), A1.w);
        }
    }
    for (; j < cc; j += 5) {
        int s = sIdx[wid][j];
        uint4 u = *(const uint4*)(xw + (size_t)s * 48 + cp);
        if (PRESCALED) {
            A0.x += lo16(u.x); A0.y += hi16(u.x); A0.z += lo16(u.y); A0.w += hi16(u.y);
            A1.x += lo16(u.z); A1.y += hi16(u.z); A1.z += lo16(u.w); A1.w += hi16(u.w);
        } else {
            float w = sW[wid][j];
            A0.x = fmaf(w, lo16(u.x), A0.x); A0.y = fmaf(w, hi16(u.x), A0.y);
            A0.z = fmaf(w, lo16(u.y), A0.z); A0.w = fmaf(w, hi16(u.y), A0.w);
            A1.x = fmaf(w, lo16(u.z), A1.x); A1.y = fmaf(w, hi16(u.z), A1.y);
            A1.z = fmaf(w, lo16(u.w), A1.z); A1.w = fmaf(w, hi16(u.w), A1.w);
        }
    }
    // reduce across 5 slots (pre-gather originals; lanes 0-11 hold the result)
    {
        float g0, g1, g2, g3;
        g0 = __shfl(A0.x, lane + 12); g1 = __shfl(A0.x, lane + 24); g2 = __shfl(A0.x, lane + 36); g3 = __shfl(A0.x, lane + 48);
        A0.x += g0 + g1 + g2 + g3;
        g0 = __shfl(A0.y, lane + 12); g1 = __shfl(A0.y, lane + 24); g2 = __shfl(A0.y, lane + 36); g3 = __shfl(A0.y, lane + 48);
        A0.y += g0 + g1 + g2 + g3;
        g0 = __shfl(A0.z, lane + 12); g1 = __shfl(A0.z, lane + 24); g2 = __shfl(A0.z, lane + 36); g3 = __shfl(A0.z, lane + 48);
        A0.z += g0 + g1 + g2 + g3;
        g0 = __shfl(A0.w, lane + 12); g1 = __shfl(A0.w, lane + 24); g2 = __shfl(A0.w, lane + 36); g3 = __shfl(A0.w, lane + 48);
        A0.w += g0 + g1 + g2 + g3;
        g0 = __shfl(A1.x, lane + 12); g1 = __shfl(A1.x, lane + 24); g2 = __shfl(A1.x, lane + 36); g3 = __shfl(A1.x, lane + 48);
        A1.x += g0 + g1 + g2 + g3;
        g0 = __shfl(A1.y, lane + 12); g1 = __shfl(A1.y, lane + 24); g2 = __shfl(A1.y, lane + 36); g3 = __shfl(A1.y, lane + 48);
        A1.y += g0 + g1 + g2 + g3;
        g0 = __shfl(A1.z, lane + 12); g1 = __shfl(A1.z, lane + 24); g2 = __shfl(A1.z, lane + 36); g3 = __shfl(A1.z, lane + 48);
        A1.z += g0 + g1 + g2 + g3;
        g0 = __shfl(A1.w, lane + 12); g1 = __shfl(A1.w, lane + 24); g2 = __shfl(A1.w, lane + 36); g3 = __shfl(A1.w, lane + 48);
        A1.w += g0 + g1 + g2 + g3;
    }

    if (lane < 12) {
        float dn = disv(cn);
        float sc = PRESCALED ? (2.f * dn) : (2.f * dn * dn);
        int cl = li * 8;
        uint4 su = *(const uint4*)(xw + (size_t)n * 48 + cp);
        float4 sv0 = make_float4(lo16(su.x), hi16(su.x), lo16(su.y), hi16(su.y));
        float4 sv1 = make_float4(lo16(su.z), hi16(su.z), lo16(su.w), hi16(su.w));
        float4 bv0 = *(const float4*)(bias + cl);
        float4 bv1 = *(const float4*)(bias + cl + 4);
        float4 rv0 = make_float4(0.f, 0.f, 0.f, 0.f);
        float4 rv1 = make_float4(0.f, 0.f, 0.f, 0.f);
        if (res) {
            rv0 = *(const float4*)(res + (size_t)n * 96 + cl);
            rv1 = *(const float4*)(res + (size_t)n * 96 + cl + 4);
        }
        float4 o0, o1;
        o0.x = rv0.x + dn * A0.x + sc * sv0.x + bv0.x;
        o0.y = rv0.y + dn * A0.y + sc * sv0.y + bv0.y;
        o0.z = rv0.z + dn * A0.z + sc * sv0.z + bv0.z;
        o0.w = rv0.w + dn * A0.w + sc * sv0.w + bv0.w;
        o1.x = rv1.x + dn * A1.x + sc * sv1.x + bv1.x;
        o1.y = rv1.y + dn * A1.y + sc * sv1.y + bv1.y;
        o1.z = rv1.z + dn * A1.z + sc * sv1.z + bv1.z;
        o1.w = rv1.w + dn * A1.w + sc * sv1.w + bv1.w;
        *(float4*)(out + (size_t)n * 96 + cl) = o0;
        *(float4*)(out + (size_t)n * 96 + cl + 4) = o1;
    }
}

// ---------------- pooling ----------------
DEVINL int ld_idx(const int* a, int i64, int i) { return i64 ? a[2 * i] : a[i]; }

DEVINL int lbound_s(const int* a, int i64, int n, int key) {
    int lo = 0, hi = n;
    while (lo < hi) { int m = (lo + hi) >> 1; if (ld_idx(a, i64, m) < key) lo = m + 1; else hi = m; }
    return lo;
}

__global__ __launch_bounds__(128) void k_pool(const float* __restrict__ h, const int* __restrict__ batch,
                                              float* __restrict__ part) {
    int i64 = detect_batch_i64(batch);
    int g = blockIdx.x / S, sch = blockIdx.x % S;
    int lo = lbound_s(batch, i64, N, g), hi = lbound_s(batch, i64, N, g + 1);
    int len = hi - lo;
    int a = lo + (int)(((long long)len * sch) / S);
    int b = lo + (int)(((long long)len * (sch + 1)) / S);
    int t = threadIdx.x;
    if (t < 96) {
        float s0 = 0.f, s1 = 0.f, m0 = -INFINITY, m1 = -INFINITY;
        int n = a;
        for (; n + 1 < b; n += 2) {
            float v0 = gelu_f(h[(size_t)n * 96 + t]);
            float v1 = gelu_f(h[(size_t)(n + 1) * 96 + t]);
            s0 += v0; s1 += v1;
            m0 = fmaxf(m0, v0); m1 = fmaxf(m1, v1);
        }
        if (n < b) {
            float v = gelu_f(h[(size_t)n * 96 + t]);
            s0 += v; m0 = fmaxf(m0, v);
        }
        part[(size_t)blockIdx.x * 192 + t] = s0 + s1;
        part[(size_t)blockIdx.x * 192 + 96 + t] = fmaxf(m0, m1);
    }
}

// ---------------- classifier head ----------------
__global__ __launch_bounds__(128) void k_cls(const float* __restrict__ part, const int* __restrict__ batch,
                                             const void* __restrict__ x,
                                             const float* __restrict__ wf, void* __restrict__ outp) {
    __shared__ float p[192];
    __shared__ float q[96];
    int i64 = detect_batch_i64(batch);
    int g = blockIdx.x, t = threadIdx.x;
    int lo = lbound_s(batch, i64, N, g), hi = lbound_s(batch, i64, N, g + 1);
    float inv = (hi > lo) ? 1.f / (float)(hi - lo) : 0.f;
    if (t < 96) {
        float sum = 0.f, mx = -INFINITY;
        for (int s = 0; s < S; ++s) {
            sum += part[(size_t)(g * S + s) * 192 + t];
            mx = fmaxf(mx, part[(size_t)(g * S + s) * 192 + 96 + t]);
        }
        p[t] = sum * inv;
        p[96 + t] = mx;
    }
    __syncthreads();
    if (t < 96) {
        float acc = wf[OFF_BC1 + t];
        const float* Wc1 = wf + OFF_WC1;
        for (int j = 0; j < 192; ++j)
            acc += p[j] * Wc1[j * 96 + t];
        q[t] = gelu_f(acc);
    }
    __syncthreads();
    if (t < 16) {
        float acc = wf[OFF_BC2 + t];
        const float* Wc2 = wf + OFF_WC2;
        for (int j = 0; j < 96; ++j)
            acc += q[j] * Wc2[j * 16 + t];
        if (detect_x_f32((const unsigned short*)x)) ((float*)outp)[g * 16 + t] = acc;
        else ((__hip_bfloat16*)outp)[g * 16 + t] = __float2bfloat16(acc);
    }
}

extern "C" void kernel_launch(void* const* d_in, const int* in_sizes, int n_in,
                              void* d_out, int out_size, void* d_ws, size_t ws_size,
                              hipStream_t stream) {
    const void* x    = d_in[0];
    const int* eidx  = (const int*)d_in[1];
    const int* batch = (const int*)d_in[2];
    (void)in_sizes; (void)n_in; (void)out_size; (void)ws_size;

    char* w = (char*)d_ws;
    size_t off = 0;
    auto take = [&](size_t bytes) { size_t o = off; off += (bytes + 511) & ~(size_t)511; return o; };
    int*      cnt  = (int*)     (w + take((size_t)N * 4));
    float*    wf   = (float*)   (w + take((size_t)WF_TOT * 4));
    int*      ell  = (int*)     (w + take((size_t)N * ELLW * 4));   // 12.8 MB
    unsigned* bufA = (unsigned*)(w + take((size_t)N * 48 * 4));     // bf16-pair packed xw
    float*    bufH = (float*)   (w + take((size_t)N * 96 * 4));
    float*    part = (float*)   (w + take((size_t)G * S * 192 * 4));

    // 1: weight convert + cnt zero
    k_prep<<<CVB, 256, 0, stream>>>(d_in[3], d_in[5], d_in[7], d_in[9], d_in[11],
                                    d_in[4], d_in[6], d_in[8], d_in[10], d_in[12],
                                    x, wf, cnt);
    // 2: fused direct ELL scatter + gemm0
    k_sg<<<3 * GEMB, 128, 0, stream>>>(x, wf + OFF_W0, eidx, cnt, ell, bufA);

    int aggr_grid = (N + 3) / 4;
    // 3-7: aggr/gemm chain
    k_aggr<false><<<aggr_grid, 256, 0, stream>>>(bufA, nullptr, ell, cnt, wf + OFF_B0, bufH);
    k_gemm<H, 48, true><<<GEMB, 128, 0, stream>>>(bufH, wf + OFF_W1, cnt, bufA);
    k_aggr<true><<<aggr_grid, 256, 0, stream>>>(bufA, bufH, ell, cnt, wf + OFF_B1, bufH);
    k_gemm<H, 48, true><<<GEMB, 128, 0, stream>>>(bufH, wf + OFF_W2, cnt, bufA);
    k_aggr<true><<<aggr_grid, 256, 0, stream>>>(bufA, bufH, ell, cnt, wf + OFF_B2, bufH);

    // 8-9: pooling + classifier
    k_pool<<<G * S, 128, 0, stream>>>(bufH, batch, part);
    k_cls<<<G, 128, 0, stream>>>(part, batch, x, wf, d_out);
}